// Round 15
// baseline (356.879 us; speedup 1.0000x reference)
//
#include <hip/hip_runtime.h>
#include <hip/hip_bf16.h>

typedef __attribute__((ext_vector_type(8))) short short8;
typedef __attribute__((ext_vector_type(4))) float f32x4;

#define DEVI static __device__ __forceinline__

constexpr int Bb = 2, Ss = 2048, Hh = 32, KVc = 4, Dc = 128;
constexpr float EPSc = 1e-6f;
constexpr float SCALEc = 0.08838834764831845f;  // 1/sqrt(128)
constexpr float LOG2Ec = 1.4426950408889634f;
constexpr float SCALE2c = SCALEc * LOG2Ec;      // exp2-domain pre-scale

DEVI float bf2f(short s) {
  unsigned u = ((unsigned)(unsigned short)s) << 16;
  float f; __builtin_memcpy(&f, &u, 4); return f;
}
DEVI short f2bf(float f) {
  __hip_bfloat16 h = __float2bfloat16(f);
  unsigned short u; __builtin_memcpy(&u, &h, 2); return (short)u;
}
// bare v_exp_f32: D = 2^S0 (handles -inf -> 0 in hardware). libm exp2f lowers
// to a slow precise path (r12: +13us attn); __expf adds a multiply (r13: +3us).
DEVI float ex2(float x) {
  float r; asm("v_exp_f32 %0, %1" : "=v"(r) : "v"(x)); return r;
}

// async global->LDS, 16B per lane. LDS dest must be linear (base + lane*16).
#define GLDS(gsrc, ldst) __builtin_amdgcn_global_load_lds( \
    (const __attribute__((address_space(1))) void*)(gsrc), \
    (__attribute__((address_space(3))) void*)(ldst), 16, 0, 0)

// ---------------- fused f32 -> bf16 convert (5 segments, 1 launch) ----------------
struct Cvt5 { const float* src[5]; short* dst[5]; };
__global__ void cvt_all(Cvt5 a) {
  // float4 counts: x 2097152, wq 2097152, wk 262144, wv 262144, wo 2097152
  constexpr int CUM[6] = {0, 2097152, 4194304, 4456448, 4718592, 6815744};
  const int stride = gridDim.x * blockDim.x;
  for (int i = blockIdx.x * blockDim.x + threadIdx.x; i < 6815744; i += stride) {
    int s = 0;
#pragma unroll
    for (int t = 1; t < 5; ++t) if (i >= CUM[t]) s = t;
    int j = i - CUM[s];
    float4 v = ((const float4*)a.src[s])[j];
    short4 o;
    o.x = f2bf(v.x); o.y = f2bf(v.y); o.z = f2bf(v.z); o.w = f2bf(v.w);
    ((short4*)a.dst[s])[j] = o;
  }
}

// ---------------- Q RMSNorm + RoPE, block-per-token (cos/sin shared x32 heads) --
// Grid 4096 = (b,s). 256 threads = 4 waves x 8 heads. In-lane rotate-half
// (d <-> d+64). Output pre-scaled by SCALE*log2(e) for exp2-domain softmax.
// r14 lesson: doing this inside the GEMM epilogue cost ~50us of VALU+scatter;
// as a standalone memory-bound pass it is ~71MB ~= 13us.
__global__ void qnorm_rope(short* __restrict__ q,
                           const float* __restrict__ cosb,
                           const float* __restrict__ sinb,
                           const float* __restrict__ qnw)
{
  __shared__ float lc[128], ls[128];
  const int m = blockIdx.x;          // b*2048 + s
  const int tid = threadIdx.x, lane = tid & 63, wvi = tid >> 6;
  if (tid < 128)      lc[tid]       = cosb[(size_t)m * 128 + tid];
  else                ls[tid - 128] = sinb[(size_t)m * 128 + (tid - 128)];
  __syncthreads();
  const float w1 = qnw[lane], w2 = qnw[lane + 64];
  const float c1 = lc[lane], c2 = lc[lane + 64];
  const float s1 = ls[lane], s2 = ls[lane + 64];
  short* base = q + (size_t)m * 4096;
#pragma unroll
  for (int hh = 0; hh < 8; ++hh) {
    short* row = base + (wvi * 8 + hh) * 128;
    float x1 = bf2f(row[lane]), x2 = bf2f(row[lane + 64]);
    float ss = x1 * x1 + x2 * x2;
    ss += __shfl_xor(ss, 32); ss += __shfl_xor(ss, 16); ss += __shfl_xor(ss, 8);
    ss += __shfl_xor(ss, 4);  ss += __shfl_xor(ss, 2);  ss += __shfl_xor(ss, 1);
    float inv = rsqrtf(ss * (1.0f / 128.0f) + EPSc);
    float n1 = x1 * inv * w1, n2 = x2 * inv * w2;
    row[lane]      = f2bf((n1 * c1 - n2 * s1) * SCALE2c);
    row[lane + 64] = f2bf((n2 * c2 + n1 * s2) * SCALE2c);
  }
}

// ---------------- 8-phase 256x256 Q-GEMM: q_raw = x @ wq^T (plain store) --------
// Grid 16x16 = 256 blocks = exactly 1/CU. 512 threads = 8 waves (4m x 2n).
// r14 budget analysis: the fused norm epilogue made this ~106us; plain store
// should return it to the m201-class ~50us. Norm moved to qnorm_rope.
__launch_bounds__(512, 2)
__global__ void gemm8q(const short* __restrict__ A,
                       const short* __restrict__ Bp,
                       short* __restrict__ oq,
                       int K)
{
  __shared__ short lA[2][256 * 64];
  __shared__ short lB[2][256 * 64];

  const int tid = threadIdx.x, lane = tid & 63;
  const int wvi = tid >> 6;
  const int l15 = lane & 15, g = lane >> 4;
  const int wm = wvi >> 1, wn = wvi & 1;
  const int m0 = blockIdx.x * 256;
  const int n0 = blockIdx.y * 256;

  f32x4 acc[4][8] = {};

  auto stA = [&](int half, int slot, int kt) {
#pragma unroll
    for (int j = 0; j < 2; ++j) {
      int rr = j * 64 + (tid >> 3);
      int grow = ((rr >> 5) << 6) + half * 32 + (rr & 31);
      GLDS(A + (size_t)(m0 + grow) * K + kt * 64 + (((tid & 7) ^ (rr & 7)) << 3),
           &lA[slot][(half * 128 + j * 64) * 64 + tid * 8]);
    }
  };
  auto stB = [&](int half, int slot, int kt) {
#pragma unroll
    for (int j = 0; j < 2; ++j) {
      int rr = j * 64 + (tid >> 3);
      int gn = ((rr >> 6) << 7) + half * 64 + (rr & 63);
      GLDS(Bp + (size_t)(n0 + gn) * K + kt * 64 + (((tid & 7) ^ (rr & 7)) << 3),
           &lB[slot][(half * 128 + j * 64) * 64 + tid * 8]);
    }
  };

#define PH(SLOT, MH, NH, STG, GT) do {                                          \
    short8 afr[2][2], bfr[4][2];                                                \
    _Pragma("unroll")                                                           \
    for (int mi2 = 0; mi2 < 2; ++mi2) {                                         \
      int rp = (MH) * 128 + wm * 32 + mi2 * 16 + l15;                           \
      _Pragma("unroll")                                                         \
      for (int kk = 0; kk < 2; ++kk)                                            \
        afr[mi2][kk] = *(const short8*)(&lA[SLOT][rp * 64 +                     \
                         (((kk * 4 + g) ^ (rp & 7)) << 3)]);                    \
    }                                                                           \
    _Pragma("unroll")                                                           \
    for (int nj = 0; nj < 4; ++nj) {                                            \
      int rp = (NH) * 128 + wn * 64 + nj * 16 + l15;                            \
      _Pragma("unroll")                                                         \
      for (int kk = 0; kk < 2; ++kk)                                            \
        bfr[nj][kk] = *(const short8*)(&lB[SLOT][rp * 64 +                      \
                         (((kk * 4 + g) ^ (rp & 7)) << 3)]);                    \
    }                                                                           \
    STG;                                                                        \
    asm volatile("" ::: "memory");                                              \
    __builtin_amdgcn_s_barrier();                                               \
    __builtin_amdgcn_s_setprio(1);                                              \
    _Pragma("unroll")                                                           \
    for (int mi2 = 0; mi2 < 2; ++mi2)                                           \
      _Pragma("unroll")                                                         \
      for (int nj = 0; nj < 4; ++nj)                                            \
        _Pragma("unroll")                                                       \
        for (int kk = 0; kk < 2; ++kk)                                          \
          acc[(MH)*2 + mi2][(NH)*4 + nj] =                                      \
            __builtin_amdgcn_mfma_f32_16x16x32_bf16(afr[mi2][kk], bfr[nj][kk],  \
                acc[(MH)*2 + mi2][(NH)*4 + nj], 0, 0, 0);                       \
    __builtin_amdgcn_s_setprio(0);                                              \
    GT;                                                                         \
    asm volatile("" ::: "memory");                                              \
    __builtin_amdgcn_s_barrier();                                               \
  } while (0)

  const int nit = K >> 7;

  stA(0, 0, 0); stB(0, 0, 0); stA(1, 0, 0); stB(1, 0, 0);
  stA(0, 1, 1); stB(0, 1, 1);
  asm volatile("s_waitcnt vmcnt(4)" ::: "memory");
  __builtin_amdgcn_s_barrier();

  for (int it = 0; it < nit; ++it) {
    const int kt1 = 2 * it + 1;
    const int k2 = 2 * it + 2, k3 = 2 * it + 3;
    const bool pre = (it + 1 < nit);
    PH(0, 0, 0, { stA(1, 1, kt1); }, {});                               // p0
    PH(0, 0, 1, { stB(1, 1, kt1); }, {});                               // p1
    PH(0, 1, 0, { if (pre) stA(0, 0, k2); }, {});                       // p2
    PH(0, 1, 1, { if (pre) stB(0, 0, k2); },
               { if (pre) asm volatile("s_waitcnt vmcnt(4)" ::: "memory");
                 else     asm volatile("s_waitcnt vmcnt(0)" ::: "memory"); }); // p3
    PH(1, 0, 0, { if (pre) stA(1, 0, k2); }, {});                       // p4
    PH(1, 0, 1, { if (pre) stB(1, 0, k2); }, {});                       // p5
    PH(1, 1, 0, { if (pre) stA(0, 1, k3); }, {});                       // p6
    PH(1, 1, 1, { if (pre) stB(0, 1, k3); },
               { if (pre) asm volatile("s_waitcnt vmcnt(4)" ::: "memory"); }); // p7
  }
#undef PH

  // ---- plain epilogue: raw bf16 store ----
#pragma unroll
  for (int mi = 0; mi < 4; ++mi)
#pragma unroll
    for (int r = 0; r < 4; ++r) {
      int m = m0 + wm * 64 + mi * 16 + g * 4 + r;
#pragma unroll
      for (int ni = 0; ni < 8; ++ni)
        oq[(size_t)m * 4096 + n0 + wn * 128 + ni * 16 + l15] = f2bf(acc[mi][ni][r]);
    }
}

// ---------------- 8-phase 128x256 out-proj GEMM (r6-measured ~52us) -------------
// out = ao @ wo^T, f32 row-major [4096][2048]. BM=128, BN=256, BK=64, K=4096.
// Grid (32, 8) = 256 blocks = 1/CU. 512 threads = 8 waves (2m x 4n).
__launch_bounds__(512, 2)
__global__ void gemm8o(const short* __restrict__ A,
                       const short* __restrict__ Bp,
                       float* __restrict__ of)
{
  constexpr int K = 4096;
  __shared__ short lA[2][128 * 64];   // 32 KiB
  __shared__ short lB[2][256 * 64];   // 64 KiB

  const int tid = threadIdx.x, lane = tid & 63;
  const int wvi = tid >> 6;
  const int l15 = lane & 15, g = lane >> 4;
  const int wm = wvi >> 2, wn = wvi & 3;
  const int m0 = blockIdx.x * 128;
  const int n0 = blockIdx.y * 256;

  f32x4 acc[4][4] = {};

  auto stA = [&](int half, int slot, int kt) {
    int rr = tid >> 3;
    int grow = ((rr >> 5) << 6) + half * 32 + (rr & 31);
    GLDS(A + (size_t)(m0 + grow) * K + kt * 64 + (((tid & 7) ^ (rr & 7)) << 3),
         &lA[slot][(half * 64) * 64 + tid * 8]);
  };
  auto stB = [&](int half, int slot, int kt) {
#pragma unroll
    for (int j = 0; j < 2; ++j) {
      int rr = j * 64 + (tid >> 3);
      int gn = ((rr >> 5) << 6) + half * 32 + (rr & 31);
      GLDS(Bp + (size_t)(n0 + gn) * K + kt * 64 + (((tid & 7) ^ (rr & 7)) << 3),
           &lB[slot][(half * 128 + j * 64) * 64 + tid * 8]);
    }
  };

#define PH(SLOT, MH, NH, STG, GT) do {                                          \
    short8 afr[2][2], bfr[2][2];                                                \
    _Pragma("unroll")                                                           \
    for (int mi2 = 0; mi2 < 2; ++mi2) {                                         \
      int rp = (MH) * 64 + wm * 32 + mi2 * 16 + l15;                            \
      _Pragma("unroll")                                                         \
      for (int kk = 0; kk < 2; ++kk)                                            \
        afr[mi2][kk] = *(const short8*)(&lA[SLOT][rp * 64 +                     \
                         (((kk * 4 + g) ^ (rp & 7)) << 3)]);                    \
    }                                                                           \
    _Pragma("unroll")                                                           \
    for (int nj = 0; nj < 2; ++nj) {                                            \
      int rp = (NH) * 128 + wn * 32 + nj * 16 + l15;                            \
      _Pragma("unroll")                                                         \
      for (int kk = 0; kk < 2; ++kk)                                            \
        bfr[nj][kk] = *(const short8*)(&lB[SLOT][rp * 64 +                      \
                         (((kk * 4 + g) ^ (rp & 7)) << 3)]);                    \
    }                                                                           \
    STG;                                                                        \
    asm volatile("" ::: "memory");                                              \
    __builtin_amdgcn_s_barrier();                                               \
    __builtin_amdgcn_s_setprio(1);                                              \
    _Pragma("unroll")                                                           \
    for (int mi2 = 0; mi2 < 2; ++mi2)                                           \
      _Pragma("unroll")                                                         \
      for (int nj = 0; nj < 2; ++nj)                                            \
        _Pragma("unroll")                                                       \
        for (int kk = 0; kk < 2; ++kk)                                          \
          acc[(MH)*2 + mi2][(NH)*2 + nj] =                                      \
            __builtin_amdgcn_mfma_f32_16x16x32_bf16(afr[mi2][kk], bfr[nj][kk],  \
                acc[(MH)*2 + mi2][(NH)*2 + nj], 0, 0, 0);                       \
    __builtin_amdgcn_s_setprio(0);                                              \
    GT;                                                                         \
    asm volatile("" ::: "memory");                                              \
    __builtin_amdgcn_s_barrier();                                               \
  } while (0)

  const int nit = K >> 7;   // 32

  stA(0, 0, 0); stB(0, 0, 0); stA(1, 0, 0); stB(1, 0, 0);
  stA(0, 1, 1); stB(0, 1, 1);
  asm volatile("s_waitcnt vmcnt(3)" ::: "memory");
  __builtin_amdgcn_s_barrier();

  for (int it = 0; it < nit; ++it) {
    const int kt1 = 2 * it + 1;
    const int k2 = 2 * it + 2, k3 = 2 * it + 3;
    const bool pre = (it + 1 < nit);
    PH(0, 0, 0, { stA(1, 1, kt1); }, {});                               // p0
    PH(0, 0, 1, { stB(1, 1, kt1); }, {});                               // p1
    PH(0, 1, 0, { if (pre) stA(0, 0, k2); }, {});                       // p2
    PH(0, 1, 1, { if (pre) stB(0, 0, k2); },
               { if (pre) asm volatile("s_waitcnt vmcnt(3)" ::: "memory");
                 else     asm volatile("s_waitcnt vmcnt(0)" ::: "memory"); }); // p3
    PH(1, 0, 0, { if (pre) stA(1, 0, k2); }, {});                       // p4
    PH(1, 0, 1, { if (pre) stB(1, 0, k2); }, {});                       // p5
    PH(1, 1, 0, { if (pre) stA(0, 1, k3); }, {});                       // p6
    PH(1, 1, 1, { if (pre) stB(0, 1, k3); },
               { if (pre) asm volatile("s_waitcnt vmcnt(3)" ::: "memory"); }); // p7
  }
#undef PH

  // ---- epilogue: f32 row-major [4096][2048] ----
#pragma unroll
  for (int mi = 0; mi < 4; ++mi)
#pragma unroll
    for (int r = 0; r < 4; ++r) {
      int m = m0 + wm * 64 + mi * 16 + g * 4 + r;
#pragma unroll
      for (int ni = 0; ni < 4; ++ni)
        of[(size_t)m * 2048 + n0 + wn * 64 + ni * 16 + l15] = acc[mi][ni][r];
    }
}

// ---------------- 2-phase 128x128 GEMM (KV only) --------------------------------
// nt<4: k = x@wk^T -> norm+rope -> [b][kv][s][d]; nt>=4: v^T -> [b][kv][d][s].
__launch_bounds__(256, 4)
__global__ void gemm2(const short* __restrict__ A,
                      const short* __restrict__ B1,
                      const short* __restrict__ B2,
                      short* __restrict__ ok,
                      short* __restrict__ ov,
                      const float* __restrict__ cosb,
                      const float* __restrict__ sinb,
                      const float* __restrict__ knw,
                      int K)
{
  __shared__ short lA[2][128 * 32];
  __shared__ short lB[2][128 * 32];
  const int tid = threadIdx.x;
  const int lane = tid & 63;
  const int wvi = tid >> 6;
  const int l15 = lane & 15, g = lane >> 4;
  const int m0 = blockIdx.x * 128;
  const int nt = blockIdx.y;
  const short* Bp; int n0, region;
  if (nt < 4) { Bp = B1; n0 = nt * 128;       region = 1; }
  else        { Bp = B2; n0 = (nt - 4) * 128; region = 2; }

  const int wrow = wvi * 32;
  const int srow = tid >> 2, schunk = tid & 3;

  f32x4 acc[2][8] = {};

  auto STAGE = [&](int ks, int bufi) {
    const int k0 = ks * 32;
#pragma unroll
    for (int c = 0; c < 2; ++c) {
      int row = c * 64 + srow;
      int gc = schunk ^ ((row >> 1) & 3);
      GLDS(A  + (size_t)(m0 + row) * K + k0 + gc * 8, &lA[bufi][(c * 256 + tid) * 8]);
      GLDS(Bp + (size_t)(n0 + row) * K + k0 + gc * 8, &lB[bufi][(c * 256 + tid) * 8]);
    }
  };

  const int nks = K >> 5;
  STAGE(0, 0);
  STAGE(1, 1);

  for (int ks = 0; ks < nks; ++ks) {
    const int cb = ks & 1;
    if (ks + 1 < nks) asm volatile("s_waitcnt vmcnt(4)" ::: "memory");
    else              asm volatile("s_waitcnt vmcnt(0)" ::: "memory");
    __builtin_amdgcn_s_barrier();
    asm volatile("" ::: "memory");

    short8 afr[2], bfr[8];
#pragma unroll
    for (int i = 0; i < 2; ++i) {
      int ra = wrow + i * 16 + l15;
      afr[i] = *(const short8*)(&lA[cb][0] + ra * 32 + ((g ^ ((ra >> 1) & 3)) * 8));
    }
#pragma unroll
    for (int i = 0; i < 8; ++i) {
      int rb = i * 16 + l15;
      bfr[i] = *(const short8*)(&lB[cb][0] + rb * 32 + ((g ^ ((rb >> 1) & 3)) * 8));
    }
#pragma unroll
    for (int mi = 0; mi < 2; ++mi)
#pragma unroll
      for (int ni = 0; ni < 8; ++ni)
        acc[mi][ni] = __builtin_amdgcn_mfma_f32_16x16x32_bf16(afr[mi], bfr[ni], acc[mi][ni], 0, 0, 0);

    asm volatile("" ::: "memory");
    __builtin_amdgcn_s_barrier();
    if (ks + 2 < nks) STAGE(ks + 2, cb);
  }

  // ---- epilogue ----
  if (region == 2) {
#pragma unroll
    for (int mi = 0; mi < 2; ++mi)
#pragma unroll
      for (int r = 0; r < 4; ++r) {
        int m = m0 + wrow + mi * 16 + g * 4 + r;
        int b = m >> 11, s = m & 2047;
#pragma unroll
        for (int ni = 0; ni < 8; ++ni) {
          int n = n0 + ni * 16 + l15;
          int kvi = n >> 7, d = n & 127;
          ov[(((size_t)b * KVc + kvi) * 128 + d) * Ss + s] = f2bf(acc[mi][ni][r]);
        }
      }
  } else {
    float w8[8];
#pragma unroll
    for (int ni = 0; ni < 8; ++ni) w8[ni] = knw[ni * 16 + l15];
#pragma unroll
    for (int mi = 0; mi < 2; ++mi)
#pragma unroll
      for (int r = 0; r < 4; ++r) {
        int m = m0 + wrow + mi * 16 + g * 4 + r;
        int b = m >> 11, s = m & 2047;
        float xv[8];
        float ssq = 0.f;
#pragma unroll
        for (int ni = 0; ni < 8; ++ni) { xv[ni] = acc[mi][ni][r]; ssq += xv[ni] * xv[ni]; }
        ssq += __shfl_xor(ssq, 1);
        ssq += __shfl_xor(ssq, 2);
        ssq += __shfl_xor(ssq, 4);
        ssq += __shfl_xor(ssq, 8);
        float inv = rsqrtf(ssq * (1.0f / 128.0f) + EPSc);
        float xn[8];
#pragma unroll
        for (int ni = 0; ni < 8; ++ni) xn[ni] = xv[ni] * inv * w8[ni];
        const float* cpr = cosb + ((size_t)b * Ss + s) * Dc;
        const float* spr = sinb + ((size_t)b * Ss + s) * Dc;
#pragma unroll
        for (int ni = 0; ni < 8; ++ni) {
          int dl = ni * 16 + l15;
          float c = cpr[dl], sn = spr[dl];
          float rot = (ni < 4) ? -xn[ni + 4] : xn[ni - 4];
          float o = xn[ni] * c + rot * sn;
          int n = n0 + dl;
          int kvi = n >> 7, d = n & 127;
          ok[(((size_t)b * KVc + kvi) * Ss + s) * 128 + d] = f2bf(o);
        }
      }
  }
}

// ---------------- Flash attention (GQA, causal) -- r7 structure + v_exp ---------
// 4 waves x 32 q-rows = 128-row q tile per block. Causal pairing: block pi
// handles q-tiles (pi, 15-pi) sequentially -> every block does 34 k-iters.
// KVBLK=64, double-buffered LDS, counted vmcnt (never drain-0 in loop).
// Swapped QK^T: mfma(A=K, B=Q) -> lane holds S^T[k_local=4g+r][q_local=l15].
// Q pre-scaled by log2(e)/sqrt(D): softmax in exp2 domain via bare v_exp_f32.
// Defer-max THR=11 (log2 units) skips the O-rescale on most tiles.
__launch_bounds__(256, 2)
__global__ void attn_fwd(const short* __restrict__ qb,
                         const short* __restrict__ kbuf,
                         const short* __restrict__ vtbuf,
                         short* __restrict__ ob)
{
  __shared__ short lK[2][64 * 128];   // 32 KiB
  __shared__ short lV[2][128 * 64];   // 32 KiB
  __shared__ short lP[4][32 * 32];    //  8 KiB
  const int tid = threadIdx.x, lane = tid & 63, wvi = tid >> 6;
  const int l15 = lane & 15, g = lane >> 4;
  const int pi = blockIdx.x, h = blockIdx.y, b = blockIdx.z;
  const int kv = h >> 3;              // G = 8
  const short* kp = kbuf  + ((size_t)b * KVc + kv) * Ss * 128;
  const short* vp = vtbuf + ((size_t)b * KVc + kv) * 128 * Ss;
  const int krow = tid >> 4, kch = tid & 15;   // K tile [64][128]: 16 chunks/row
  const int vrow = tid >> 3, vch = tid & 7;    // V^T tile [128][64]: 8 chunks/row

  for (int which = 0; which < 2; ++which) {
    const int qt = which ? (15 - pi) : pi;
    const int qwb = qt * 128 + (wvi & 3) * 32;
    const int nkt = 2 * qt + 2;       // 64-key tiles needed

    short8 qf[2][4];
#pragma unroll
    for (int qs = 0; qs < 2; ++qs)
#pragma unroll
      for (int dc = 0; dc < 4; ++dc)
        qf[qs][dc] = *(const short8*)(qb + (size_t)(b * Ss + qwb + qs * 16 + l15) * 4096
                                         + h * 128 + dc * 32 + g * 8);

    f32x4 oacc[2][8] = {};
    float mrun[2] = { -__builtin_inff(), -__builtin_inff() };
    float lrun[2] = { 0.f, 0.f };

    auto STAGE = [&](int kt, int bufi) {   // 8 GLDS per lane
      const int kb0 = kt * 64;
#pragma unroll
      for (int c = 0; c < 4; ++c) {        // K [64][128]
        int r = c * 16 + krow;
        int gc = kch ^ (r & 7);
        GLDS(kp + (size_t)(kb0 + r) * 128 + gc * 8, &lK[bufi][(c * 256 + tid) * 8]);
      }
#pragma unroll
      for (int c = 0; c < 4; ++c) {        // V^T [128][64]
        int r = c * 32 + vrow;
        int gc = vch ^ (r & 7);
        GLDS(vp + (size_t)r * Ss + kb0 + gc * 8, &lV[bufi][(c * 256 + tid) * 8]);
      }
    };

    STAGE(0, 0);
    STAGE(1, 1);                        // nkt >= 2 always

    for (int kt = 0; kt < nkt; ++kt) {
      const int cb = kt & 1;
      if (kt + 1 < nkt) asm volatile("s_waitcnt vmcnt(8)" ::: "memory");
      else              asm volatile("s_waitcnt vmcnt(0)" ::: "memory");
      __builtin_amdgcn_s_barrier();
      asm volatile("" ::: "memory");

#pragma unroll
      for (int half = 0; half < 2; ++half) {
        const int kb0 = kt * 64 + half * 32;
        if (kb0 <= qwb + 31) {
          short8 kf[2][4];
#pragma unroll
          for (int ks = 0; ks < 2; ++ks)
#pragma unroll
            for (int dc = 0; dc < 4; ++dc) {
              int row = half * 32 + ks * 16 + l15;
              kf[ks][dc] = *(const short8*)(&lK[cb][0] + row * 128 + (((dc * 4 + g) ^ (row & 7)) * 8));
            }
          f32x4 st[2][2] = {};
          __builtin_amdgcn_s_setprio(1);
#pragma unroll
          for (int qs = 0; qs < 2; ++qs)
#pragma unroll
            for (int ks = 0; ks < 2; ++ks)
#pragma unroll
              for (int dc = 0; dc < 4; ++dc)
                st[qs][ks] = __builtin_amdgcn_mfma_f32_16x16x32_bf16(kf[ks][dc], qf[qs][dc], st[qs][ks], 0, 0, 0);
          __builtin_amdgcn_s_setprio(0);

          const bool need_mask = (kb0 + 31 > qwb);
#pragma unroll
          for (int qs = 0; qs < 2; ++qs) {
            const int qg = qwb + qs * 16 + l15;
            float p[8];
            float tmax = -__builtin_inff();
#pragma unroll
            for (int ks = 0; ks < 2; ++ks)
#pragma unroll
              for (int r = 0; r < 4; ++r) {
                float v = st[qs][ks][r];
                if (need_mask && (kb0 + ks * 16 + g * 4 + r > qg)) v = -__builtin_inff();
                p[ks * 4 + r] = v;
                tmax = fmaxf(tmax, v);
              }
            tmax = fmaxf(tmax, __shfl_xor(tmax, 16));
            tmax = fmaxf(tmax, __shfl_xor(tmax, 32));
            // defer-max: only rescale O when the running max grows by > 11 (log2)
            float m_use = mrun[qs];
            if (__any(tmax > m_use + 11.0f)) {
              float mnew = fmaxf(m_use, tmax);
              float scl = ex2(m_use - mnew);   // -inf first tile -> 0
              lrun[qs] *= scl;
              mrun[qs] = mnew;
#pragma unroll
              for (int r = 0; r < 4; ++r) {
                float sc = __shfl(scl, g * 4 + r);
#pragma unroll
                for (int dt = 0; dt < 8; ++dt)
                  oacc[qs][dt][r] *= sc;
              }
              m_use = mnew;
            }
            float rsum = 0.f;
#pragma unroll
            for (int j = 0; j < 8; ++j) { p[j] = ex2(p[j] - m_use); rsum += p[j]; }
            rsum += __shfl_xor(rsum, 16);
            rsum += __shfl_xor(rsum, 32);
            lrun[qs] += rsum;
            {
              int row = qs * 16 + l15;
              int sw = (row >> 1) & 3;
              short* pr = lP[wvi] + row * 32;
#pragma unroll
              for (int ks = 0; ks < 2; ++ks) {
                int idx = (((2 * ks + (g >> 1)) ^ sw) * 8) + (g & 1) * 4; // k = 16ks+4g+r
                short4 pw;
                pw.x = f2bf(p[ks * 4 + 0]);
                pw.y = f2bf(p[ks * 4 + 1]);
                pw.z = f2bf(p[ks * 4 + 2]);
                pw.w = f2bf(p[ks * 4 + 3]);
                *(short4*)(pr + idx) = pw;
              }
            }
          }
          asm volatile("" ::: "memory");   // order lP writes before lP reads (in-wave)
          short8 vf[8];
#pragma unroll
          for (int dt = 0; dt < 8; ++dt) {
            int row = dt * 16 + l15;
            vf[dt] = *(const short8*)(&lV[cb][0] + row * 64 + (((half * 4 + g) ^ (row & 7)) * 8));
          }
          __builtin_amdgcn_s_setprio(1);
#pragma unroll
          for (int qs = 0; qs < 2; ++qs) {
            int row = qs * 16 + l15;
            short8 pf = *(const short8*)(lP[wvi] + row * 32 + ((g ^ ((row >> 1) & 3)) * 8));
#pragma unroll
            for (int dt = 0; dt < 8; ++dt)
              oacc[qs][dt] = __builtin_amdgcn_mfma_f32_16x16x32_bf16(pf, vf[dt], oacc[qs][dt], 0, 0, 0);
          }
          __builtin_amdgcn_s_setprio(0);
          asm volatile("" ::: "memory");
        }
      }

      asm volatile("" ::: "memory");
      __builtin_amdgcn_s_barrier();      // everyone done reading buf[cb]
      if (kt + 2 < nkt) STAGE(kt + 2, cb);
    }

#pragma unroll
    for (int qs = 0; qs < 2; ++qs)
#pragma unroll
      for (int r = 0; r < 4; ++r) {
        float inv = 1.0f / __shfl(lrun[qs], g * 4 + r);
        int qrow = qwb + qs * 16 + g * 4 + r;
        short* op = ob + (size_t)(b * Ss + qrow) * 4096 + h * 128;
#pragma unroll
        for (int dt = 0; dt < 8; ++dt)
          op[dt * 16 + l15] = f2bf(oacc[qs][dt][r] * inv);
      }
  }
}

// ---------------- host ----------------
extern "C" void kernel_launch(void* const* d_in, const int* in_sizes, int n_in,
                              void* d_out, int out_size, void* d_ws, size_t ws_size,
                              hipStream_t stream) {
  const float* x    = (const float*)d_in[0];
  const float* cosb = (const float*)d_in[1];
  const float* sinb = (const float*)d_in[2];
  const float* wq   = (const float*)d_in[3];
  const float* wk   = (const float*)d_in[4];
  const float* wv   = (const float*)d_in[5];
  const float* wo   = (const float*)d_in[6];
  const float* qw   = (const float*)d_in[7];
  const float* kw   = (const float*)d_in[8];

  size_t off = 0;
  auto alloc = [&](size_t bytes) {
    char* p = (char*)d_ws + off;
    off += (bytes + 255) & ~(size_t)255;
    return p;
  };
  short* x_bf  = (short*)alloc((size_t)8388608 * 2);
  short* wq_bf = (short*)alloc((size_t)8388608 * 2);
  short* wk_bf = (short*)alloc((size_t)1048576 * 2);
  short* wv_bf = (short*)alloc((size_t)1048576 * 2);
  short* wo_bf = (short*)alloc((size_t)8388608 * 2);
  short* q_bf  = (short*)alloc((size_t)16777216 * 2);
  short* k_bf  = (short*)alloc((size_t)2097152 * 2);
  short* v_bf  = (short*)alloc((size_t)2097152 * 2);
  short* ao_bf = (short*)alloc((size_t)16777216 * 2);

  Cvt5 ca;
  ca.src[0] = x;    ca.dst[0] = x_bf;
  ca.src[1] = wq;   ca.dst[1] = wq_bf;
  ca.src[2] = wk;   ca.dst[2] = wk_bf;
  ca.src[3] = wv;   ca.dst[3] = wv_bf;
  ca.src[4] = wo;   ca.dst[4] = wo_bf;
  cvt_all<<<2048, 256, 0, stream>>>(ca);

  gemm8q<<<dim3(16, 16), 512, 0, stream>>>(x_bf, wq_bf, q_bf, 2048);
  qnorm_rope<<<4096, 256, 0, stream>>>(q_bf, cosb, sinb, qw);
  gemm2<<<dim3(32, 8), 256, 0, stream>>>(x_bf, wk_bf, wv_bf, k_bf, v_bf,
                                         cosb, sinb, kw, 2048);
  attn_fwd<<<dim3(8, 32, 2), 256, 0, stream>>>(q_bf, k_bf, v_bf, ao_bf);
  gemm8o<<<dim3(32, 8), 512, 0, stream>>>(ao_bf, wo_bf, (float*)d_out);
}

// Round 16
// 342.826 us; speedup vs baseline: 1.0410x; 1.0410x over previous
//
#include <hip/hip_runtime.h>
#include <hip/hip_bf16.h>

typedef __attribute__((ext_vector_type(8))) short short8;
typedef __attribute__((ext_vector_type(4))) float f32x4;

#define DEVI static __device__ __forceinline__

constexpr int Bb = 2, Ss = 2048, Hh = 32, KVc = 4, Dc = 128;
constexpr float EPSc = 1e-6f;
constexpr float SCALEc = 0.08838834764831845f;  // 1/sqrt(128)
constexpr float LOG2Ec = 1.4426950408889634f;
constexpr float SCALE2c = SCALEc * LOG2Ec;      // exp2-domain pre-scale

DEVI float bf2f(short s) {
  unsigned u = ((unsigned)(unsigned short)s) << 16;
  float f; __builtin_memcpy(&f, &u, 4); return f;
}
DEVI short f2bf(float f) {
  __hip_bfloat16 h = __float2bfloat16(f);
  unsigned short u; __builtin_memcpy(&u, &h, 2); return (short)u;
}
// bare v_exp_f32: D = 2^S0 (handles -inf -> 0 in hardware). libm exp2f lowers
// to a slow precise path (r12: +13us attn); __expf adds a multiply (r13: -16us won).
DEVI float ex2(float x) {
  float r; asm("v_exp_f32 %0, %1" : "=v"(r) : "v"(x)); return r;
}

// async global->LDS, 16B per lane. LDS dest must be linear (base + lane*16).
#define GLDS(gsrc, ldst) __builtin_amdgcn_global_load_lds( \
    (const __attribute__((address_space(1))) void*)(gsrc), \
    (__attribute__((address_space(3))) void*)(ldst), 16, 0, 0)

// ---------------- fused f32 -> bf16 convert (5 segments, 1 launch) ----------------
struct Cvt5 { const float* src[5]; short* dst[5]; };
__global__ void cvt_all(Cvt5 a) {
  // float4 counts: x 2097152, wq 2097152, wk 262144, wv 262144, wo 2097152
  constexpr int CUM[6] = {0, 2097152, 4194304, 4456448, 4718592, 6815744};
  const int stride = gridDim.x * blockDim.x;
  for (int i = blockIdx.x * blockDim.x + threadIdx.x; i < 6815744; i += stride) {
    int s = 0;
#pragma unroll
    for (int t = 1; t < 5; ++t) if (i >= CUM[t]) s = t;
    int j = i - CUM[s];
    float4 v = ((const float4*)a.src[s])[j];
    short4 o;
    o.x = f2bf(v.x); o.y = f2bf(v.y); o.z = f2bf(v.z); o.w = f2bf(v.w);
    ((short4*)a.dst[s])[j] = o;
  }
}

// ---------------- 8-phase 256x256 Q-GEMM: q = x @ wq^T, fused RMSNorm+RoPE ------
// 1D grid 256 blocks = 1/CU, XCD-aware decode: x=bid&7 (the XCD), k=bid>>3;
// mt=2x+(k&1), nt=k>>1. Each XCD owns m-tiles {2x,2x+1} (A stays in its 4MB L2:
// 2MB) and sweeps all n with both m-tiles adjacent -> each B panel fetched once
// per XCD. Fetch ~380MB -> ~144MB (r15 budget: this kernel was ~104us, mostly
// HBM over-fetch). 512 threads = 8 waves (4m x 2n), per-wave 64x128 = full
// head-dim -> in-lane RMSNorm+RoPE epilogue; q pre-scaled by SCALE*log2(e).
__launch_bounds__(512, 2)
__global__ void gemm8q(const short* __restrict__ A,
                       const short* __restrict__ Bp,
                       short* __restrict__ oq,
                       const float* __restrict__ cosb,
                       const float* __restrict__ sinb,
                       const float* __restrict__ qnw,
                       int K)
{
  __shared__ short lA[2][256 * 64];
  __shared__ short lB[2][256 * 64];

  const int tid = threadIdx.x, lane = tid & 63;
  const int wvi = tid >> 6;
  const int l15 = lane & 15, g = lane >> 4;
  const int wm = wvi >> 1, wn = wvi & 1;
  const int bid = blockIdx.x;
  const int xcd = bid & 7, kk2 = bid >> 3;      // kk2 in 0..31
  const int m0 = (2 * xcd + (kk2 & 1)) * 256;   // XCD-stationary A
  const int n0 = (kk2 >> 1) * 256;

  f32x4 acc[4][8] = {};

  auto stA = [&](int half, int slot, int kt) {
#pragma unroll
    for (int j = 0; j < 2; ++j) {
      int rr = j * 64 + (tid >> 3);
      int grow = ((rr >> 5) << 6) + half * 32 + (rr & 31);
      GLDS(A + (size_t)(m0 + grow) * K + kt * 64 + (((tid & 7) ^ (rr & 7)) << 3),
           &lA[slot][(half * 128 + j * 64) * 64 + tid * 8]);
    }
  };
  auto stB = [&](int half, int slot, int kt) {
#pragma unroll
    for (int j = 0; j < 2; ++j) {
      int rr = j * 64 + (tid >> 3);
      int gn = ((rr >> 6) << 7) + half * 64 + (rr & 63);
      GLDS(Bp + (size_t)(n0 + gn) * K + kt * 64 + (((tid & 7) ^ (rr & 7)) << 3),
           &lB[slot][(half * 128 + j * 64) * 64 + tid * 8]);
    }
  };

#define PH(SLOT, MH, NH, STG, GT) do {                                          \
    short8 afr[2][2], bfr[4][2];                                                \
    _Pragma("unroll")                                                           \
    for (int mi2 = 0; mi2 < 2; ++mi2) {                                         \
      int rp = (MH) * 128 + wm * 32 + mi2 * 16 + l15;                           \
      _Pragma("unroll")                                                         \
      for (int kk = 0; kk < 2; ++kk)                                            \
        afr[mi2][kk] = *(const short8*)(&lA[SLOT][rp * 64 +                     \
                         (((kk * 4 + g) ^ (rp & 7)) << 3)]);                    \
    }                                                                           \
    _Pragma("unroll")                                                           \
    for (int nj = 0; nj < 4; ++nj) {                                            \
      int rp = (NH) * 128 + wn * 64 + nj * 16 + l15;                            \
      _Pragma("unroll")                                                         \
      for (int kk = 0; kk < 2; ++kk)                                            \
        bfr[nj][kk] = *(const short8*)(&lB[SLOT][rp * 64 +                      \
                         (((kk * 4 + g) ^ (rp & 7)) << 3)]);                    \
    }                                                                           \
    STG;                                                                        \
    asm volatile("" ::: "memory");                                              \
    __builtin_amdgcn_s_barrier();                                               \
    __builtin_amdgcn_s_setprio(1);                                              \
    _Pragma("unroll")                                                           \
    for (int mi2 = 0; mi2 < 2; ++mi2)                                           \
      _Pragma("unroll")                                                         \
      for (int nj = 0; nj < 4; ++nj)                                            \
        _Pragma("unroll")                                                       \
        for (int kk = 0; kk < 2; ++kk)                                          \
          acc[(MH)*2 + mi2][(NH)*4 + nj] =                                      \
            __builtin_amdgcn_mfma_f32_16x16x32_bf16(afr[mi2][kk], bfr[nj][kk],  \
                acc[(MH)*2 + mi2][(NH)*4 + nj], 0, 0, 0);                       \
    __builtin_amdgcn_s_setprio(0);                                              \
    GT;                                                                         \
    asm volatile("" ::: "memory");                                              \
    __builtin_amdgcn_s_barrier();                                               \
  } while (0)

  const int nit = K >> 7;

  stA(0, 0, 0); stB(0, 0, 0); stA(1, 0, 0); stB(1, 0, 0);
  stA(0, 1, 1); stB(0, 1, 1);
  asm volatile("s_waitcnt vmcnt(4)" ::: "memory");
  __builtin_amdgcn_s_barrier();

  for (int it = 0; it < nit; ++it) {
    const int kt1 = 2 * it + 1;
    const int k2 = 2 * it + 2, k3 = 2 * it + 3;
    const bool pre = (it + 1 < nit);
    PH(0, 0, 0, { stA(1, 1, kt1); }, {});                               // p0
    PH(0, 0, 1, { stB(1, 1, kt1); }, {});                               // p1
    PH(0, 1, 0, { if (pre) stA(0, 0, k2); }, {});                       // p2
    PH(0, 1, 1, { if (pre) stB(0, 0, k2); },
               { if (pre) asm volatile("s_waitcnt vmcnt(4)" ::: "memory");
                 else     asm volatile("s_waitcnt vmcnt(0)" ::: "memory"); }); // p3
    PH(1, 0, 0, { if (pre) stA(1, 0, k2); }, {});                       // p4
    PH(1, 0, 1, { if (pre) stB(1, 0, k2); }, {});                       // p5
    PH(1, 1, 0, { if (pre) stA(0, 1, k3); }, {});                       // p6
    PH(1, 1, 1, { if (pre) stB(0, 1, k3); },
               { if (pre) asm volatile("s_waitcnt vmcnt(4)" ::: "memory"); }); // p7
  }
#undef PH

  // ---- epilogue: fused RMSNorm (full D=128 in-lane) + RoPE + scale*log2e ----
  float w8[8];
#pragma unroll
  for (int ni = 0; ni < 8; ++ni) w8[ni] = qnw[ni * 16 + l15];
#pragma unroll
  for (int mi = 0; mi < 4; ++mi)
#pragma unroll
    for (int r = 0; r < 4; ++r) {
      int m = m0 + wm * 64 + mi * 16 + g * 4 + r;
      int b = m >> 11, s = m & 2047;
      float xv[8];
      float ssq = 0.f;
#pragma unroll
      for (int ni = 0; ni < 8; ++ni) { xv[ni] = acc[mi][ni][r]; ssq += xv[ni] * xv[ni]; }
      ssq += __shfl_xor(ssq, 1);
      ssq += __shfl_xor(ssq, 2);
      ssq += __shfl_xor(ssq, 4);
      ssq += __shfl_xor(ssq, 8);
      float inv = rsqrtf(ssq * (1.0f / 128.0f) + EPSc);
      float xn[8];
#pragma unroll
      for (int ni = 0; ni < 8; ++ni) xn[ni] = xv[ni] * inv * w8[ni];
      const float* cpr = cosb + ((size_t)b * Ss + s) * Dc;
      const float* spr = sinb + ((size_t)b * Ss + s) * Dc;
#pragma unroll
      for (int ni = 0; ni < 8; ++ni) {
        int d = ni * 16 + l15;
        float c = cpr[d], sn = spr[d];
        float rot = (ni < 4) ? -xn[ni + 4] : xn[ni - 4];
        float o = xn[ni] * c + rot * sn;
        oq[(size_t)m * 4096 + n0 + wn * 128 + d] = f2bf(o * SCALE2c);
      }
    }
}

// ---------------- 2-phase 128x128 GEMM (proven r5 structure) --------------------
// MODE 0: KV. nt<4: k = x@wk^T -> norm+rope -> [b][kv][s][d]; nt>=4: v^T.
// MODE 1: out-proj, f32 row-major out (N=2048).
template<int MODE>
__launch_bounds__(256, 4)
__global__ void gemm2(const short* __restrict__ A,
                      const short* __restrict__ B1,
                      const short* __restrict__ B2,
                      short* __restrict__ ok,
                      short* __restrict__ ov,
                      float* __restrict__ of,
                      const float* __restrict__ cosb,
                      const float* __restrict__ sinb,
                      const float* __restrict__ knw,
                      int K)
{
  __shared__ short lA[2][128 * 32];
  __shared__ short lB[2][128 * 32];
  const int tid = threadIdx.x;
  const int lane = tid & 63;
  const int wvi = tid >> 6;
  const int l15 = lane & 15, g = lane >> 4;
  const int m0 = blockIdx.x * 128;
  const int nt = blockIdx.y;
  const short* Bp; int n0, region;
  if (MODE == 0) {
    if (nt < 4) { Bp = B1; n0 = nt * 128;       region = 1; }
    else        { Bp = B2; n0 = (nt - 4) * 128; region = 2; }
  } else { Bp = B1; n0 = nt * 128; region = 3; }

  const int wrow = wvi * 32;
  const int srow = tid >> 2, schunk = tid & 3;

  f32x4 acc[2][8] = {};

  auto STAGE = [&](int ks, int bufi) {
    const int k0 = ks * 32;
#pragma unroll
    for (int c = 0; c < 2; ++c) {
      int row = c * 64 + srow;
      int gc = schunk ^ ((row >> 1) & 3);
      GLDS(A  + (size_t)(m0 + row) * K + k0 + gc * 8, &lA[bufi][(c * 256 + tid) * 8]);
      GLDS(Bp + (size_t)(n0 + row) * K + k0 + gc * 8, &lB[bufi][(c * 256 + tid) * 8]);
    }
  };

  const int nks = K >> 5;
  STAGE(0, 0);
  STAGE(1, 1);

  for (int ks = 0; ks < nks; ++ks) {
    const int cb = ks & 1;
    if (ks + 1 < nks) asm volatile("s_waitcnt vmcnt(4)" ::: "memory");
    else              asm volatile("s_waitcnt vmcnt(0)" ::: "memory");
    __builtin_amdgcn_s_barrier();
    asm volatile("" ::: "memory");

    short8 afr[2], bfr[8];
#pragma unroll
    for (int i = 0; i < 2; ++i) {
      int ra = wrow + i * 16 + l15;
      afr[i] = *(const short8*)(&lA[cb][0] + ra * 32 + ((g ^ ((ra >> 1) & 3)) * 8));
    }
#pragma unroll
    for (int i = 0; i < 8; ++i) {
      int rb = i * 16 + l15;
      bfr[i] = *(const short8*)(&lB[cb][0] + rb * 32 + ((g ^ ((rb >> 1) & 3)) * 8));
    }
#pragma unroll
    for (int mi = 0; mi < 2; ++mi)
#pragma unroll
      for (int ni = 0; ni < 8; ++ni)
        acc[mi][ni] = __builtin_amdgcn_mfma_f32_16x16x32_bf16(afr[mi], bfr[ni], acc[mi][ni], 0, 0, 0);

    asm volatile("" ::: "memory");
    __builtin_amdgcn_s_barrier();
    if (ks + 2 < nks) STAGE(ks + 2, cb);
  }

  // ---- epilogue ----
  if (MODE == 1) {
#pragma unroll
    for (int mi = 0; mi < 2; ++mi)
#pragma unroll
      for (int r = 0; r < 4; ++r) {
        int m = m0 + wrow + mi * 16 + g * 4 + r;
#pragma unroll
        for (int ni = 0; ni < 8; ++ni)
          of[(size_t)m * 2048 + n0 + ni * 16 + l15] = acc[mi][ni][r];
      }
  } else if (region == 2) {
#pragma unroll
    for (int mi = 0; mi < 2; ++mi)
#pragma unroll
      for (int r = 0; r < 4; ++r) {
        int m = m0 + wrow + mi * 16 + g * 4 + r;
        int b = m >> 11, s = m & 2047;
#pragma unroll
        for (int ni = 0; ni < 8; ++ni) {
          int n = n0 + ni * 16 + l15;
          int kvi = n >> 7, d = n & 127;
          ov[(((size_t)b * KVc + kvi) * 128 + d) * Ss + s] = f2bf(acc[mi][ni][r]);
        }
      }
  } else {
    float w8[8];
#pragma unroll
    for (int ni = 0; ni < 8; ++ni) w8[ni] = knw[ni * 16 + l15];
#pragma unroll
    for (int mi = 0; mi < 2; ++mi)
#pragma unroll
      for (int r = 0; r < 4; ++r) {
        int m = m0 + wrow + mi * 16 + g * 4 + r;
        int b = m >> 11, s = m & 2047;
        float xv[8];
        float ssq = 0.f;
#pragma unroll
        for (int ni = 0; ni < 8; ++ni) { xv[ni] = acc[mi][ni][r]; ssq += xv[ni] * xv[ni]; }
        ssq += __shfl_xor(ssq, 1);
        ssq += __shfl_xor(ssq, 2);
        ssq += __shfl_xor(ssq, 4);
        ssq += __shfl_xor(ssq, 8);
        float inv = rsqrtf(ssq * (1.0f / 128.0f) + EPSc);
        float xn[8];
#pragma unroll
        for (int ni = 0; ni < 8; ++ni) xn[ni] = xv[ni] * inv * w8[ni];
        const float* cpr = cosb + ((size_t)b * Ss + s) * Dc;
        const float* spr = sinb + ((size_t)b * Ss + s) * Dc;
#pragma unroll
        for (int ni = 0; ni < 8; ++ni) {
          int dl = ni * 16 + l15;
          float c = cpr[dl], sn = spr[dl];
          float rot = (ni < 4) ? -xn[ni + 4] : xn[ni - 4];
          float o = xn[ni] * c + rot * sn;
          int n = n0 + dl;
          int kvi = n >> 7, d = n & 127;
          ok[(((size_t)b * KVc + kvi) * Ss + s) * 128 + d] = f2bf(o);
        }
      }
  }
}

// ---------------- Flash attention (GQA, causal) -- r7 structure + v_exp ---------
// 4 waves x 32 q-rows = 128-row q tile per block. Causal pairing: block pi
// handles q-tiles (pi, 15-pi) sequentially -> every block does 34 k-iters.
// KVBLK=64, double-buffered LDS, counted vmcnt (never drain-0 in loop).
// Swapped QK^T: mfma(A=K, B=Q) -> lane holds S^T[k_local=4g+r][q_local=l15].
// Q pre-scaled by log2(e)/sqrt(D): softmax in exp2 domain via bare v_exp_f32.
// Defer-max THR=11 (log2 units) skips the O-rescale on most tiles.
__launch_bounds__(256, 2)
__global__ void attn_fwd(const short* __restrict__ qb,
                         const short* __restrict__ kbuf,
                         const short* __restrict__ vtbuf,
                         short* __restrict__ ob)
{
  __shared__ short lK[2][64 * 128];   // 32 KiB
  __shared__ short lV[2][128 * 64];   // 32 KiB
  __shared__ short lP[4][32 * 32];    //  8 KiB
  const int tid = threadIdx.x, lane = tid & 63, wvi = tid >> 6;
  const int l15 = lane & 15, g = lane >> 4;
  const int pi = blockIdx.x, h = blockIdx.y, b = blockIdx.z;
  const int kv = h >> 3;              // G = 8
  const short* kp = kbuf  + ((size_t)b * KVc + kv) * Ss * 128;
  const short* vp = vtbuf + ((size_t)b * KVc + kv) * 128 * Ss;
  const int krow = tid >> 4, kch = tid & 15;   // K tile [64][128]: 16 chunks/row
  const int vrow = tid >> 3, vch = tid & 7;    // V^T tile [128][64]: 8 chunks/row

  for (int which = 0; which < 2; ++which) {
    const int qt = which ? (15 - pi) : pi;
    const int qwb = qt * 128 + (wvi & 3) * 32;
    const int nkt = 2 * qt + 2;       // 64-key tiles needed

    short8 qf[2][4];
#pragma unroll
    for (int qs = 0; qs < 2; ++qs)
#pragma unroll
      for (int dc = 0; dc < 4; ++dc)
        qf[qs][dc] = *(const short8*)(qb + (size_t)(b * Ss + qwb + qs * 16 + l15) * 4096
                                         + h * 128 + dc * 32 + g * 8);

    f32x4 oacc[2][8] = {};
    float mrun[2] = { -__builtin_inff(), -__builtin_inff() };
    float lrun[2] = { 0.f, 0.f };

    auto STAGE = [&](int kt, int bufi) {   // 8 GLDS per lane
      const int kb0 = kt * 64;
#pragma unroll
      for (int c = 0; c < 4; ++c) {        // K [64][128]
        int r = c * 16 + krow;
        int gc = kch ^ (r & 7);
        GLDS(kp + (size_t)(kb0 + r) * 128 + gc * 8, &lK[bufi][(c * 256 + tid) * 8]);
      }
#pragma unroll
      for (int c = 0; c < 4; ++c) {        // V^T [128][64]
        int r = c * 32 + vrow;
        int gc = vch ^ (r & 7);
        GLDS(vp + (size_t)r * Ss + kb0 + gc * 8, &lV[bufi][(c * 256 + tid) * 8]);
      }
    };

    STAGE(0, 0);
    STAGE(1, 1);                        // nkt >= 2 always

    for (int kt = 0; kt < nkt; ++kt) {
      const int cb = kt & 1;
      if (kt + 1 < nkt) asm volatile("s_waitcnt vmcnt(8)" ::: "memory");
      else              asm volatile("s_waitcnt vmcnt(0)" ::: "memory");
      __builtin_amdgcn_s_barrier();
      asm volatile("" ::: "memory");

#pragma unroll
      for (int half = 0; half < 2; ++half) {
        const int kb0 = kt * 64 + half * 32;
        if (kb0 <= qwb + 31) {
          short8 kf[2][4];
#pragma unroll
          for (int ks = 0; ks < 2; ++ks)
#pragma unroll
            for (int dc = 0; dc < 4; ++dc) {
              int row = half * 32 + ks * 16 + l15;
              kf[ks][dc] = *(const short8*)(&lK[cb][0] + row * 128 + (((dc * 4 + g) ^ (row & 7)) * 8));
            }
          f32x4 st[2][2] = {};
          __builtin_amdgcn_s_setprio(1);
#pragma unroll
          for (int qs = 0; qs < 2; ++qs)
#pragma unroll
            for (int ks = 0; ks < 2; ++ks)
#pragma unroll
              for (int dc = 0; dc < 4; ++dc)
                st[qs][ks] = __builtin_amdgcn_mfma_f32_16x16x32_bf16(kf[ks][dc], qf[qs][dc], st[qs][ks], 0, 0, 0);
          __builtin_amdgcn_s_setprio(0);

          const bool need_mask = (kb0 + 31 > qwb);
#pragma unroll
          for (int qs = 0; qs < 2; ++qs) {
            const int qg = qwb + qs * 16 + l15;
            float p[8];
            float tmax = -__builtin_inff();
#pragma unroll
            for (int ks = 0; ks < 2; ++ks)
#pragma unroll
              for (int r = 0; r < 4; ++r) {
                float v = st[qs][ks][r];
                if (need_mask && (kb0 + ks * 16 + g * 4 + r > qg)) v = -__builtin_inff();
                p[ks * 4 + r] = v;
                tmax = fmaxf(tmax, v);
              }
            tmax = fmaxf(tmax, __shfl_xor(tmax, 16));
            tmax = fmaxf(tmax, __shfl_xor(tmax, 32));
            // defer-max: only rescale O when the running max grows by > 11 (log2)
            float m_use = mrun[qs];
            if (__any(tmax > m_use + 11.0f)) {
              float mnew = fmaxf(m_use, tmax);
              float scl = ex2(m_use - mnew);   // -inf first tile -> 0
              lrun[qs] *= scl;
              mrun[qs] = mnew;
#pragma unroll
              for (int r = 0; r < 4; ++r) {
                float sc = __shfl(scl, g * 4 + r);
#pragma unroll
                for (int dt = 0; dt < 8; ++dt)
                  oacc[qs][dt][r] *= sc;
              }
              m_use = mnew;
            }
            float rsum = 0.f;
#pragma unroll
            for (int j = 0; j < 8; ++j) { p[j] = ex2(p[j] - m_use); rsum += p[j]; }
            rsum += __shfl_xor(rsum, 16);
            rsum += __shfl_xor(rsum, 32);
            lrun[qs] += rsum;
            {
              int row = qs * 16 + l15;
              int sw = (row >> 1) & 3;
              short* pr = lP[wvi] + row * 32;
#pragma unroll
              for (int ks = 0; ks < 2; ++ks) {
                int idx = (((2 * ks + (g >> 1)) ^ sw) * 8) + (g & 1) * 4; // k = 16ks+4g+r
                short4 pw;
                pw.x = f2bf(p[ks * 4 + 0]);
                pw.y = f2bf(p[ks * 4 + 1]);
                pw.z = f2bf(p[ks * 4 + 2]);
                pw.w = f2bf(p[ks * 4 + 3]);
                *(short4*)(pr + idx) = pw;
              }
            }
          }
          asm volatile("" ::: "memory");   // order lP writes before lP reads (in-wave)
          short8 vf[8];
#pragma unroll
          for (int dt = 0; dt < 8; ++dt) {
            int row = dt * 16 + l15;
            vf[dt] = *(const short8*)(&lV[cb][0] + row * 64 + (((half * 4 + g) ^ (row & 7)) * 8));
          }
          __builtin_amdgcn_s_setprio(1);
#pragma unroll
          for (int qs = 0; qs < 2; ++qs) {
            int row = qs * 16 + l15;
            short8 pf = *(const short8*)(lP[wvi] + row * 32 + ((g ^ ((row >> 1) & 3)) * 8));
#pragma unroll
            for (int dt = 0; dt < 8; ++dt)
              oacc[qs][dt] = __builtin_amdgcn_mfma_f32_16x16x32_bf16(pf, vf[dt], oacc[qs][dt], 0, 0, 0);
          }
          __builtin_amdgcn_s_setprio(0);
          asm volatile("" ::: "memory");
        }
      }

      asm volatile("" ::: "memory");
      __builtin_amdgcn_s_barrier();      // everyone done reading buf[cb]
      if (kt + 2 < nkt) STAGE(kt + 2, cb);
    }

#pragma unroll
    for (int qs = 0; qs < 2; ++qs)
#pragma unroll
      for (int r = 0; r < 4; ++r) {
        float inv = 1.0f / __shfl(lrun[qs], g * 4 + r);
        int qrow = qwb + qs * 16 + g * 4 + r;
        short* op = ob + (size_t)(b * Ss + qrow) * 4096 + h * 128;
#pragma unroll
        for (int dt = 0; dt < 8; ++dt)
          op[dt * 16 + l15] = f2bf(oacc[qs][dt][r] * inv);
      }
  }
}

// ---------------- host ----------------
extern "C" void kernel_launch(void* const* d_in, const int* in_sizes, int n_in,
                              void* d_out, int out_size, void* d_ws, size_t ws_size,
                              hipStream_t stream) {
  const float* x    = (const float*)d_in[0];
  const float* cosb = (const float*)d_in[1];
  const float* sinb = (const float*)d_in[2];
  const float* wq   = (const float*)d_in[3];
  const float* wk   = (const float*)d_in[4];
  const float* wv   = (const float*)d_in[5];
  const float* wo   = (const float*)d_in[6];
  const float* qw   = (const float*)d_in[7];
  const float* kw   = (const float*)d_in[8];

  size_t off = 0;
  auto alloc = [&](size_t bytes) {
    char* p = (char*)d_ws + off;
    off += (bytes + 255) & ~(size_t)255;
    return p;
  };
  short* x_bf  = (short*)alloc((size_t)8388608 * 2);
  short* wq_bf = (short*)alloc((size_t)8388608 * 2);
  short* wk_bf = (short*)alloc((size_t)1048576 * 2);
  short* wv_bf = (short*)alloc((size_t)1048576 * 2);
  short* wo_bf = (short*)alloc((size_t)8388608 * 2);
  short* q_bf  = (short*)alloc((size_t)16777216 * 2);
  short* k_bf  = (short*)alloc((size_t)2097152 * 2);
  short* v_bf  = (short*)alloc((size_t)2097152 * 2);
  short* ao_bf = (short*)alloc((size_t)16777216 * 2);

  Cvt5 ca;
  ca.src[0] = x;    ca.dst[0] = x_bf;
  ca.src[1] = wq;   ca.dst[1] = wq_bf;
  ca.src[2] = wk;   ca.dst[2] = wk_bf;
  ca.src[3] = wv;   ca.dst[3] = wv_bf;
  ca.src[4] = wo;   ca.dst[4] = wo_bf;
  cvt_all<<<2048, 256, 0, stream>>>(ca);

  gemm8q<<<256, 512, 0, stream>>>(x_bf, wq_bf, q_bf, cosb, sinb, qw, 2048);
  gemm2<0><<<dim3(32, 8), 256, 0, stream>>>(x_bf, wk_bf, wv_bf, k_bf, v_bf, nullptr,
                                            cosb, sinb, kw, 2048);
  attn_fwd<<<dim3(8, 32, 2), 256, 0, stream>>>(q_bf, k_bf, v_bf, ao_bf);
  gemm2<1><<<dim3(32, 16), 256, 0, stream>>>(ao_bf, wo_bf, nullptr, nullptr, nullptr,
                                             (float*)d_out, nullptr, nullptr, nullptr, 4096);
}

// Round 17
// 339.075 us; speedup vs baseline: 1.0525x; 1.0111x over previous
//
#include <hip/hip_runtime.h>
#include <hip/hip_bf16.h>

typedef __attribute__((ext_vector_type(8))) short short8;
typedef __attribute__((ext_vector_type(4))) float f32x4;

#define DEVI static __device__ __forceinline__

constexpr int Bb = 2, Ss = 2048, Hh = 32, KVc = 4, Dc = 128;
constexpr float EPSc = 1e-6f;
constexpr float SCALEc = 0.08838834764831845f;  // 1/sqrt(128)
constexpr float LOG2Ec = 1.4426950408889634f;
constexpr float SCALE2c = SCALEc * LOG2Ec;      // exp2-domain pre-scale

DEVI float bf2f(short s) {
  unsigned u = ((unsigned)(unsigned short)s) << 16;
  float f; __builtin_memcpy(&f, &u, 4); return f;
}
DEVI short f2bf(float f) {
  __hip_bfloat16 h = __float2bfloat16(f);
  unsigned short u; __builtin_memcpy(&u, &h, 2); return (short)u;
}
// bare v_exp_f32: D = 2^S0 (handles -inf -> 0 in hardware). libm exp2f lowers
// to a slow precise path (r12: +13us attn); __expf adds a multiply (r13: -16us won).
DEVI float ex2(float x) {
  float r; asm("v_exp_f32 %0, %1" : "=v"(r) : "v"(x)); return r;
}

// async global->LDS, 16B per lane. LDS dest must be linear (base + lane*16).
#define GLDS(gsrc, ldst) __builtin_amdgcn_global_load_lds( \
    (const __attribute__((address_space(1))) void*)(gsrc), \
    (__attribute__((address_space(3))) void*)(ldst), 16, 0, 0)

// ---------------- fused f32 -> bf16 convert (5 segments, 1 launch) ----------------
struct Cvt5 { const float* src[5]; short* dst[5]; };
__global__ void cvt_all(Cvt5 a) {
  // float4 counts: x 2097152, wq 2097152, wk 262144, wv 262144, wo 2097152
  constexpr int CUM[6] = {0, 2097152, 4194304, 4456448, 4718592, 6815744};
  const int stride = gridDim.x * blockDim.x;
  for (int i = blockIdx.x * blockDim.x + threadIdx.x; i < 6815744; i += stride) {
    int s = 0;
#pragma unroll
    for (int t = 1; t < 5; ++t) if (i >= CUM[t]) s = t;
    int j = i - CUM[s];
    float4 v = ((const float4*)a.src[s])[j];
    short4 o;
    o.x = f2bf(v.x); o.y = f2bf(v.y); o.z = f2bf(v.z); o.w = f2bf(v.w);
    ((short4*)a.dst[s])[j] = o;
  }
}

// ---------------- 8-phase 256x256 Q-GEMM: q = x @ wq^T, fused RMSNorm+RoPE ------
// 1D grid 256 blocks = 1/CU, XCD-aware decode (r16: neutral, kept — zero risk).
// Phase pairs (p0,p1),(p2,p3),... share (SLOT,MH) -> A-fragments are loaded
// only on even phases and reused on odd (12->avg 10 ds_read_b128/phase; the
// phase is LDS-issue-bound: ~144cyc LDS vs ~77cyc MFMA at 12 reads).
// 512 threads = 8 waves (4m x 2n), per-wave 64x128 = full head-dim -> in-lane
// RMSNorm+RoPE epilogue; q pre-scaled by SCALE*log2(e).
__launch_bounds__(512, 2)
__global__ void gemm8q(const short* __restrict__ A,
                       const short* __restrict__ Bp,
                       short* __restrict__ oq,
                       const float* __restrict__ cosb,
                       const float* __restrict__ sinb,
                       const float* __restrict__ qnw,
                       int K)
{
  __shared__ short lA[2][256 * 64];
  __shared__ short lB[2][256 * 64];

  const int tid = threadIdx.x, lane = tid & 63;
  const int wvi = tid >> 6;
  const int l15 = lane & 15, g = lane >> 4;
  const int wm = wvi >> 1, wn = wvi & 1;
  const int bid = blockIdx.x;
  const int xcd = bid & 7, kk2 = bid >> 3;      // kk2 in 0..31
  const int m0 = (2 * xcd + (kk2 & 1)) * 256;   // XCD-stationary A
  const int n0 = (kk2 >> 1) * 256;

  f32x4 acc[4][8] = {};
  short8 afr[2][2];                              // persists across phase pairs

  auto stA = [&](int half, int slot, int kt) {
#pragma unroll
    for (int j = 0; j < 2; ++j) {
      int rr = j * 64 + (tid >> 3);
      int grow = ((rr >> 5) << 6) + half * 32 + (rr & 31);
      GLDS(A + (size_t)(m0 + grow) * K + kt * 64 + (((tid & 7) ^ (rr & 7)) << 3),
           &lA[slot][(half * 128 + j * 64) * 64 + tid * 8]);
    }
  };
  auto stB = [&](int half, int slot, int kt) {
#pragma unroll
    for (int j = 0; j < 2; ++j) {
      int rr = j * 64 + (tid >> 3);
      int gn = ((rr >> 6) << 7) + half * 64 + (rr & 63);
      GLDS(Bp + (size_t)(n0 + gn) * K + kt * 64 + (((tid & 7) ^ (rr & 7)) << 3),
           &lB[slot][(half * 128 + j * 64) * 64 + tid * 8]);
    }
  };

// LDA=1 on even phases (NH==0): (re)load afr for this (SLOT,MH); odd phases reuse.
#define PH(SLOT, MH, NH, LDA, STG, GT) do {                                     \
    if (LDA) {                                                                  \
      _Pragma("unroll")                                                         \
      for (int mi2 = 0; mi2 < 2; ++mi2) {                                       \
        int rp = (MH) * 128 + wm * 32 + mi2 * 16 + l15;                         \
        _Pragma("unroll")                                                       \
        for (int kk = 0; kk < 2; ++kk)                                          \
          afr[mi2][kk] = *(const short8*)(&lA[SLOT][rp * 64 +                   \
                           (((kk * 4 + g) ^ (rp & 7)) << 3)]);                  \
      }                                                                         \
    }                                                                           \
    short8 bfr[4][2];                                                           \
    _Pragma("unroll")                                                           \
    for (int nj = 0; nj < 4; ++nj) {                                            \
      int rp = (NH) * 128 + wn * 64 + nj * 16 + l15;                            \
      _Pragma("unroll")                                                         \
      for (int kk = 0; kk < 2; ++kk)                                            \
        bfr[nj][kk] = *(const short8*)(&lB[SLOT][rp * 64 +                      \
                         (((kk * 4 + g) ^ (rp & 7)) << 3)]);                    \
    }                                                                           \
    STG;                                                                        \
    asm volatile("" ::: "memory");                                              \
    __builtin_amdgcn_s_barrier();                                               \
    __builtin_amdgcn_s_setprio(1);                                              \
    _Pragma("unroll")                                                           \
    for (int mi2 = 0; mi2 < 2; ++mi2)                                           \
      _Pragma("unroll")                                                         \
      for (int nj = 0; nj < 4; ++nj)                                            \
        _Pragma("unroll")                                                       \
        for (int kk = 0; kk < 2; ++kk)                                          \
          acc[(MH)*2 + mi2][(NH)*4 + nj] =                                      \
            __builtin_amdgcn_mfma_f32_16x16x32_bf16(afr[mi2][kk], bfr[nj][kk],  \
                acc[(MH)*2 + mi2][(NH)*4 + nj], 0, 0, 0);                       \
    __builtin_amdgcn_s_setprio(0);                                              \
    GT;                                                                         \
    asm volatile("" ::: "memory");                                              \
    __builtin_amdgcn_s_barrier();                                               \
  } while (0)

  const int nit = K >> 7;

  stA(0, 0, 0); stB(0, 0, 0); stA(1, 0, 0); stB(1, 0, 0);
  stA(0, 1, 1); stB(0, 1, 1);
  asm volatile("s_waitcnt vmcnt(4)" ::: "memory");
  __builtin_amdgcn_s_barrier();

  for (int it = 0; it < nit; ++it) {
    const int kt1 = 2 * it + 1;
    const int k2 = 2 * it + 2, k3 = 2 * it + 3;
    const bool pre = (it + 1 < nit);
    PH(0, 0, 0, 1, { stA(1, 1, kt1); }, {});                            // p0
    PH(0, 0, 1, 0, { stB(1, 1, kt1); }, {});                            // p1
    PH(0, 1, 0, 1, { if (pre) stA(0, 0, k2); }, {});                    // p2
    PH(0, 1, 1, 0, { if (pre) stB(0, 0, k2); },
               { if (pre) asm volatile("s_waitcnt vmcnt(4)" ::: "memory");
                 else     asm volatile("s_waitcnt vmcnt(0)" ::: "memory"); }); // p3
    PH(1, 0, 0, 1, { if (pre) stA(1, 0, k2); }, {});                    // p4
    PH(1, 0, 1, 0, { if (pre) stB(1, 0, k2); }, {});                    // p5
    PH(1, 1, 0, 1, { if (pre) stA(0, 1, k3); }, {});                    // p6
    PH(1, 1, 1, 0, { if (pre) stB(0, 1, k3); },
               { if (pre) asm volatile("s_waitcnt vmcnt(4)" ::: "memory"); }); // p7
  }
#undef PH

  // ---- epilogue: fused RMSNorm (full D=128 in-lane) + RoPE + scale*log2e ----
  float w8[8];
#pragma unroll
  for (int ni = 0; ni < 8; ++ni) w8[ni] = qnw[ni * 16 + l15];
#pragma unroll
  for (int mi = 0; mi < 4; ++mi)
#pragma unroll
    for (int r = 0; r < 4; ++r) {
      int m = m0 + wm * 64 + mi * 16 + g * 4 + r;
      int b = m >> 11, s = m & 2047;
      float xv[8];
      float ssq = 0.f;
#pragma unroll
      for (int ni = 0; ni < 8; ++ni) { xv[ni] = acc[mi][ni][r]; ssq += xv[ni] * xv[ni]; }
      ssq += __shfl_xor(ssq, 1);
      ssq += __shfl_xor(ssq, 2);
      ssq += __shfl_xor(ssq, 4);
      ssq += __shfl_xor(ssq, 8);
      float inv = rsqrtf(ssq * (1.0f / 128.0f) + EPSc);
      float xn[8];
#pragma unroll
      for (int ni = 0; ni < 8; ++ni) xn[ni] = xv[ni] * inv * w8[ni];
      const float* cpr = cosb + ((size_t)b * Ss + s) * Dc;
      const float* spr = sinb + ((size_t)b * Ss + s) * Dc;
#pragma unroll
      for (int ni = 0; ni < 8; ++ni) {
        int d = ni * 16 + l15;
        float c = cpr[d], sn = spr[d];
        float rot = (ni < 4) ? -xn[ni + 4] : xn[ni - 4];
        float o = xn[ni] * c + rot * sn;
        oq[(size_t)m * 4096 + n0 + wn * 128 + d] = f2bf(o * SCALE2c);
      }
    }
}

// ---------------- 2-phase 128x128 GEMM (proven r5 structure) --------------------
// MODE 0: KV. nt<4: k = x@wk^T -> norm+rope -> [b][kv][s][d]; nt>=4: v^T.
// MODE 1: out-proj, f32 row-major out (N=2048).
template<int MODE>
__launch_bounds__(256, 4)
__global__ void gemm2(const short* __restrict__ A,
                      const short* __restrict__ B1,
                      const short* __restrict__ B2,
                      short* __restrict__ ok,
                      short* __restrict__ ov,
                      float* __restrict__ of,
                      const float* __restrict__ cosb,
                      const float* __restrict__ sinb,
                      const float* __restrict__ knw,
                      int K)
{
  __shared__ short lA[2][128 * 32];
  __shared__ short lB[2][128 * 32];
  const int tid = threadIdx.x;
  const int lane = tid & 63;
  const int wvi = tid >> 6;
  const int l15 = lane & 15, g = lane >> 4;
  const int m0 = blockIdx.x * 128;
  const int nt = blockIdx.y;
  const short* Bp; int n0, region;
  if (MODE == 0) {
    if (nt < 4) { Bp = B1; n0 = nt * 128;       region = 1; }
    else        { Bp = B2; n0 = (nt - 4) * 128; region = 2; }
  } else { Bp = B1; n0 = nt * 128; region = 3; }

  const int wrow = wvi * 32;
  const int srow = tid >> 2, schunk = tid & 3;

  f32x4 acc[2][8] = {};

  auto STAGE = [&](int ks, int bufi) {
    const int k0 = ks * 32;
#pragma unroll
    for (int c = 0; c < 2; ++c) {
      int row = c * 64 + srow;
      int gc = schunk ^ ((row >> 1) & 3);
      GLDS(A  + (size_t)(m0 + row) * K + k0 + gc * 8, &lA[bufi][(c * 256 + tid) * 8]);
      GLDS(Bp + (size_t)(n0 + row) * K + k0 + gc * 8, &lB[bufi][(c * 256 + tid) * 8]);
    }
  };

  const int nks = K >> 5;
  STAGE(0, 0);
  STAGE(1, 1);

  for (int ks = 0; ks < nks; ++ks) {
    const int cb = ks & 1;
    if (ks + 1 < nks) asm volatile("s_waitcnt vmcnt(4)" ::: "memory");
    else              asm volatile("s_waitcnt vmcnt(0)" ::: "memory");
    __builtin_amdgcn_s_barrier();
    asm volatile("" ::: "memory");

    short8 afr[2], bfr[8];
#pragma unroll
    for (int i = 0; i < 2; ++i) {
      int ra = wrow + i * 16 + l15;
      afr[i] = *(const short8*)(&lA[cb][0] + ra * 32 + ((g ^ ((ra >> 1) & 3)) * 8));
    }
#pragma unroll
    for (int i = 0; i < 8; ++i) {
      int rb = i * 16 + l15;
      bfr[i] = *(const short8*)(&lB[cb][0] + rb * 32 + ((g ^ ((rb >> 1) & 3)) * 8));
    }
#pragma unroll
    for (int mi = 0; mi < 2; ++mi)
#pragma unroll
      for (int ni = 0; ni < 8; ++ni)
        acc[mi][ni] = __builtin_amdgcn_mfma_f32_16x16x32_bf16(afr[mi], bfr[ni], acc[mi][ni], 0, 0, 0);

    asm volatile("" ::: "memory");
    __builtin_amdgcn_s_barrier();
    if (ks + 2 < nks) STAGE(ks + 2, cb);
  }

  // ---- epilogue ----
  if (MODE == 1) {
#pragma unroll
    for (int mi = 0; mi < 2; ++mi)
#pragma unroll
      for (int r = 0; r < 4; ++r) {
        int m = m0 + wrow + mi * 16 + g * 4 + r;
#pragma unroll
        for (int ni = 0; ni < 8; ++ni)
          of[(size_t)m * 2048 + n0 + ni * 16 + l15] = acc[mi][ni][r];
      }
  } else if (region == 2) {
#pragma unroll
    for (int mi = 0; mi < 2; ++mi)
#pragma unroll
      for (int r = 0; r < 4; ++r) {
        int m = m0 + wrow + mi * 16 + g * 4 + r;
        int b = m >> 11, s = m & 2047;
#pragma unroll
        for (int ni = 0; ni < 8; ++ni) {
          int n = n0 + ni * 16 + l15;
          int kvi = n >> 7, d = n & 127;
          ov[(((size_t)b * KVc + kvi) * 128 + d) * Ss + s] = f2bf(acc[mi][ni][r]);
        }
      }
  } else {
    float w8[8];
#pragma unroll
    for (int ni = 0; ni < 8; ++ni) w8[ni] = knw[ni * 16 + l15];
#pragma unroll
    for (int mi = 0; mi < 2; ++mi)
#pragma unroll
      for (int r = 0; r < 4; ++r) {
        int m = m0 + wrow + mi * 16 + g * 4 + r;
        int b = m >> 11, s = m & 2047;
        float xv[8];
        float ssq = 0.f;
#pragma unroll
        for (int ni = 0; ni < 8; ++ni) { xv[ni] = acc[mi][ni][r]; ssq += xv[ni] * xv[ni]; }
        ssq += __shfl_xor(ssq, 1);
        ssq += __shfl_xor(ssq, 2);
        ssq += __shfl_xor(ssq, 4);
        ssq += __shfl_xor(ssq, 8);
        float inv = rsqrtf(ssq * (1.0f / 128.0f) + EPSc);
        float xn[8];
#pragma unroll
        for (int ni = 0; ni < 8; ++ni) xn[ni] = xv[ni] * inv * w8[ni];
        const float* cpr = cosb + ((size_t)b * Ss + s) * Dc;
        const float* spr = sinb + ((size_t)b * Ss + s) * Dc;
#pragma unroll
        for (int ni = 0; ni < 8; ++ni) {
          int dl = ni * 16 + l15;
          float c = cpr[dl], sn = spr[dl];
          float rot = (ni < 4) ? -xn[ni + 4] : xn[ni - 4];
          float o = xn[ni] * c + rot * sn;
          int n = n0 + dl;
          int kvi = n >> 7, d = n & 127;
          ok[(((size_t)b * KVc + kvi) * Ss + s) * 128 + d] = f2bf(o);
        }
      }
  }
}

// ---------------- Flash attention (GQA, causal) -- r7 structure + v_exp ---------
// 4 waves x 32 q-rows = 128-row q tile per block. Causal pairing: block pi
// handles q-tiles (pi, 15-pi) sequentially -> every block does 34 k-iters.
// KVBLK=64, double-buffered LDS, counted vmcnt (never drain-0 in loop).
// Swapped QK^T: mfma(A=K, B=Q) -> lane holds S^T[k_local=4g+r][q_local=l15].
// Q pre-scaled by log2(e)/sqrt(D): softmax in exp2 domain via bare v_exp_f32.
// Defer-max THR=11 (log2 units) skips the O-rescale on most tiles.
__launch_bounds__(256, 2)
__global__ void attn_fwd(const short* __restrict__ qb,
                         const short* __restrict__ kbuf,
                         const short* __restrict__ vtbuf,
                         short* __restrict__ ob)
{
  __shared__ short lK[2][64 * 128];   // 32 KiB
  __shared__ short lV[2][128 * 64];   // 32 KiB
  __shared__ short lP[4][32 * 32];    //  8 KiB
  const int tid = threadIdx.x, lane = tid & 63, wvi = tid >> 6;
  const int l15 = lane & 15, g = lane >> 4;
  const int pi = blockIdx.x, h = blockIdx.y, b = blockIdx.z;
  const int kv = h >> 3;              // G = 8
  const short* kp = kbuf  + ((size_t)b * KVc + kv) * Ss * 128;
  const short* vp = vtbuf + ((size_t)b * KVc + kv) * 128 * Ss;
  const int krow = tid >> 4, kch = tid & 15;   // K tile [64][128]: 16 chunks/row
  const int vrow = tid >> 3, vch = tid & 7;    // V^T tile [128][64]: 8 chunks/row

  for (int which = 0; which < 2; ++which) {
    const int qt = which ? (15 - pi) : pi;
    const int qwb = qt * 128 + (wvi & 3) * 32;
    const int nkt = 2 * qt + 2;       // 64-key tiles needed

    short8 qf[2][4];
#pragma unroll
    for (int qs = 0; qs < 2; ++qs)
#pragma unroll
      for (int dc = 0; dc < 4; ++dc)
        qf[qs][dc] = *(const short8*)(qb + (size_t)(b * Ss + qwb + qs * 16 + l15) * 4096
                                         + h * 128 + dc * 32 + g * 8);

    f32x4 oacc[2][8] = {};
    float mrun[2] = { -__builtin_inff(), -__builtin_inff() };
    float lrun[2] = { 0.f, 0.f };

    auto STAGE = [&](int kt, int bufi) {   // 8 GLDS per lane
      const int kb0 = kt * 64;
#pragma unroll
      for (int c = 0; c < 4; ++c) {        // K [64][128]
        int r = c * 16 + krow;
        int gc = kch ^ (r & 7);
        GLDS(kp + (size_t)(kb0 + r) * 128 + gc * 8, &lK[bufi][(c * 256 + tid) * 8]);
      }
#pragma unroll
      for (int c = 0; c < 4; ++c) {        // V^T [128][64]
        int r = c * 32 + vrow;
        int gc = vch ^ (r & 7);
        GLDS(vp + (size_t)r * Ss + kb0 + gc * 8, &lV[bufi][(c * 256 + tid) * 8]);
      }
    };

    STAGE(0, 0);
    STAGE(1, 1);                        // nkt >= 2 always

    for (int kt = 0; kt < nkt; ++kt) {
      const int cb = kt & 1;
      if (kt + 1 < nkt) asm volatile("s_waitcnt vmcnt(8)" ::: "memory");
      else              asm volatile("s_waitcnt vmcnt(0)" ::: "memory");
      __builtin_amdgcn_s_barrier();
      asm volatile("" ::: "memory");

#pragma unroll
      for (int half = 0; half < 2; ++half) {
        const int kb0 = kt * 64 + half * 32;
        if (kb0 <= qwb + 31) {
          short8 kf[2][4];
#pragma unroll
          for (int ks = 0; ks < 2; ++ks)
#pragma unroll
            for (int dc = 0; dc < 4; ++dc) {
              int row = half * 32 + ks * 16 + l15;
              kf[ks][dc] = *(const short8*)(&lK[cb][0] + row * 128 + (((dc * 4 + g) ^ (row & 7)) * 8));
            }
          f32x4 st[2][2] = {};
          __builtin_amdgcn_s_setprio(1);
#pragma unroll
          for (int qs = 0; qs < 2; ++qs)
#pragma unroll
            for (int ks = 0; ks < 2; ++ks)
#pragma unroll
              for (int dc = 0; dc < 4; ++dc)
                st[qs][ks] = __builtin_amdgcn_mfma_f32_16x16x32_bf16(kf[ks][dc], qf[qs][dc], st[qs][ks], 0, 0, 0);
          __builtin_amdgcn_s_setprio(0);

          const bool need_mask = (kb0 + 31 > qwb);
#pragma unroll
          for (int qs = 0; qs < 2; ++qs) {
            const int qg = qwb + qs * 16 + l15;
            float p[8];
            float tmax = -__builtin_inff();
#pragma unroll
            for (int ks = 0; ks < 2; ++ks)
#pragma unroll
              for (int r = 0; r < 4; ++r) {
                float v = st[qs][ks][r];
                if (need_mask && (kb0 + ks * 16 + g * 4 + r > qg)) v = -__builtin_inff();
                p[ks * 4 + r] = v;
                tmax = fmaxf(tmax, v);
              }
            tmax = fmaxf(tmax, __shfl_xor(tmax, 16));
            tmax = fmaxf(tmax, __shfl_xor(tmax, 32));
            // defer-max: only rescale O when the running max grows by > 11 (log2)
            float m_use = mrun[qs];
            if (__any(tmax > m_use + 11.0f)) {
              float mnew = fmaxf(m_use, tmax);
              float scl = ex2(m_use - mnew);   // -inf first tile -> 0
              lrun[qs] *= scl;
              mrun[qs] = mnew;
#pragma unroll
              for (int r = 0; r < 4; ++r) {
                float sc = __shfl(scl, g * 4 + r);
#pragma unroll
                for (int dt = 0; dt < 8; ++dt)
                  oacc[qs][dt][r] *= sc;
              }
              m_use = mnew;
            }
            float rsum = 0.f;
#pragma unroll
            for (int j = 0; j < 8; ++j) { p[j] = ex2(p[j] - m_use); rsum += p[j]; }
            rsum += __shfl_xor(rsum, 16);
            rsum += __shfl_xor(rsum, 32);
            lrun[qs] += rsum;
            {
              int row = qs * 16 + l15;
              int sw = (row >> 1) & 3;
              short* pr = lP[wvi] + row * 32;
#pragma unroll
              for (int ks = 0; ks < 2; ++ks) {
                int idx = (((2 * ks + (g >> 1)) ^ sw) * 8) + (g & 1) * 4; // k = 16ks+4g+r
                short4 pw;
                pw.x = f2bf(p[ks * 4 + 0]);
                pw.y = f2bf(p[ks * 4 + 1]);
                pw.z = f2bf(p[ks * 4 + 2]);
                pw.w = f2bf(p[ks * 4 + 3]);
                *(short4*)(pr + idx) = pw;
              }
            }
          }
          asm volatile("" ::: "memory");   // order lP writes before lP reads (in-wave)
          short8 vf[8];
#pragma unroll
          for (int dt = 0; dt < 8; ++dt) {
            int row = dt * 16 + l15;
            vf[dt] = *(const short8*)(&lV[cb][0] + row * 64 + (((half * 4 + g) ^ (row & 7)) * 8));
          }
          __builtin_amdgcn_s_setprio(1);
#pragma unroll
          for (int qs = 0; qs < 2; ++qs) {
            int row = qs * 16 + l15;
            short8 pf = *(const short8*)(lP[wvi] + row * 32 + ((g ^ ((row >> 1) & 3)) * 8));
#pragma unroll
            for (int dt = 0; dt < 8; ++dt)
              oacc[qs][dt] = __builtin_amdgcn_mfma_f32_16x16x32_bf16(pf, vf[dt], oacc[qs][dt], 0, 0, 0);
          }
          __builtin_amdgcn_s_setprio(0);
          asm volatile("" ::: "memory");
        }
      }

      asm volatile("" ::: "memory");
      __builtin_amdgcn_s_barrier();      // everyone done reading buf[cb]
      if (kt + 2 < nkt) STAGE(kt + 2, cb);
    }

#pragma unroll
    for (int qs = 0; qs < 2; ++qs)
#pragma unroll
      for (int r = 0; r < 4; ++r) {
        float inv = 1.0f / __shfl(lrun[qs], g * 4 + r);
        int qrow = qwb + qs * 16 + g * 4 + r;
        short* op = ob + (size_t)(b * Ss + qrow) * 4096 + h * 128;
#pragma unroll
        for (int dt = 0; dt < 8; ++dt)
          op[dt * 16 + l15] = f2bf(oacc[qs][dt][r] * inv);
      }
  }
}

// ---------------- host ----------------
extern "C" void kernel_launch(void* const* d_in, const int* in_sizes, int n_in,
                              void* d_out, int out_size, void* d_ws, size_t ws_size,
                              hipStream_t stream) {
  const float* x    = (const float*)d_in[0];
  const float* cosb = (const float*)d_in[1];
  const float* sinb = (const float*)d_in[2];
  const float* wq   = (const float*)d_in[3];
  const float* wk   = (const float*)d_in[4];
  const float* wv   = (const float*)d_in[5];
  const float* wo   = (const float*)d_in[6];
  const float* qw   = (const float*)d_in[7];
  const float* kw   = (const float*)d_in[8];

  size_t off = 0;
  auto alloc = [&](size_t bytes) {
    char* p = (char*)d_ws + off;
    off += (bytes + 255) & ~(size_t)255;
    return p;
  };
  short* x_bf  = (short*)alloc((size_t)8388608 * 2);
  short* wq_bf = (short*)alloc((size_t)8388608 * 2);
  short* wk_bf = (short*)alloc((size_t)1048576 * 2);
  short* wv_bf = (short*)alloc((size_t)1048576 * 2);
  short* wo_bf = (short*)alloc((size_t)8388608 * 2);
  short* q_bf  = (short*)alloc((size_t)16777216 * 2);
  short* k_bf  = (short*)alloc((size_t)2097152 * 2);
  short* v_bf  = (short*)alloc((size_t)2097152 * 2);
  short* ao_bf = (short*)alloc((size_t)16777216 * 2);

  Cvt5 ca;
  ca.src[0] = x;    ca.dst[0] = x_bf;
  ca.src[1] = wq;   ca.dst[1] = wq_bf;
  ca.src[2] = wk;   ca.dst[2] = wk_bf;
  ca.src[3] = wv;   ca.dst[3] = wv_bf;
  ca.src[4] = wo;   ca.dst[4] = wo_bf;
  cvt_all<<<2048, 256, 0, stream>>>(ca);

  gemm8q<<<256, 512, 0, stream>>>(x_bf, wq_bf, q_bf, cosb, sinb, qw, 2048);
  gemm2<0><<<dim3(32, 8), 256, 0, stream>>>(x_bf, wk_bf, wv_bf, k_bf, v_bf, nullptr,
                                            cosb, sinb, kw, 2048);
  attn_fwd<<<dim3(8, 32, 2), 256, 0, stream>>>(q_bf, k_bf, v_bf, ao_bf);
  gemm2<1><<<dim3(32, 16), 256, 0, stream>>>(ao_bf, wo_bf, nullptr, nullptr, nullptr,
                                             (float*)d_out, nullptr, nullptr, nullptr, 4096);
}